// Round 6
// baseline (180.890 us; speedup 1.0000x reference)
//
#include <hip/hip_runtime.h>

#define N_NODES 50000
#define N_EDGES 800000
#define TOT (N_EDGES + N_NODES)
#define NBKT 196          // dest buckets of 256 nodes
#define BCAP 6144         // staging capacity per bucket (mean 4096 + 32 sigma)

typedef __attribute__((ext_vector_type(4))) float floatx4;
typedef __attribute__((ext_vector_type(8))) _Float16 half8;
typedef __attribute__((ext_vector_type(2))) _Float16 half2v;

// ---- workspace layout (bytes) ----
#define O_PTR   0UL          // int[N]
#define O_GF    200192UL     // int[NBKT]
#define O_FLAG  201216UL     // int[2]: [1]=indices-are-int64
#define O_DINV  201472UL     // float[N]
#define O_ESRC  401664UL     // int[TOT] 3.4MB
#define O_W1    3801856UL    // f16[128*128] (transposed [n][k])
#define O_W2    3834624UL    // f16[64*128]  (transposed [n][k])
#define O_U     3851008UL    // f16[N*128] aggregated rows; ALIASED: u32 staging[NBKT*BCAP]=4.8MB (dead before k_agg)
#define O_H16   16651008UL   // f16[N*128] dinv-prescaled h
// end: 29451008 bytes (<= 29.9MB proven footprint)

// prep: weights -> f16 transposed, zero bucket fills, probe index width.
__global__ void k_prep(const float* __restrict__ Wg, const float* __restrict__ Wf,
                       const unsigned* __restrict__ ei_raw,
                       int* gfill, _Float16* W1, _Float16* W2, int* flags) {
    int i = blockIdx.x * 256 + threadIdx.x;
    if (i < 128 * 128) { int n = i >> 7, k = i & 127; W1[i] = (_Float16)Wg[k * 128 + n]; }
    if (i < 64 * 128)  { int n = i >> 7, k = i & 127; W2[i] = (_Float16)Wf[k * 64 + n]; }
    if (i < NBKT) gfill[i] = 0;
    if (i >= 16320) {                         // last wave of block 63
        int lane = i - 16320;
        unsigned w = ei_raw[2 * lane + 1];
        unsigned long long m = __ballot(w == 0u);
        if (lane == 0) flags[1] = (__popcll(m) >= 60) ? 1 : 0;
    }
}

// Pass A: coarse-bin edges by dest>>8 into per-bucket staging runs.
__global__ __launch_bounds__(256) void k_binA(const int* __restrict__ ei,
                                              const int* __restrict__ flags,
                                              int* __restrict__ gfill,
                                              unsigned* __restrict__ staging) {
    __shared__ int cnt[NBKT];
    __shared__ int gbase[NBKT];
    int t = threadIdx.x;
    for (int i = t; i < NBKT; i += 256) cnt[i] = 0;
    __syncthreads();
    int ebase = blockIdx.x * 4096;
    bool i64 = flags[1] != 0;
    unsigned pk[16]; int rk[16]; short bk[16];
#pragma unroll
    for (int j = 0; j < 16; ++j) {
        int e = ebase + j * 256 + t;
        if (e < N_EDGES) {
            int s, d;
            if (i64) { s = ei[2 * e]; d = ei[2 * (N_EDGES + e)]; }
            else     { s = ei[e];     d = ei[N_EDGES + e]; }
            int b = d >> 8;
            bk[j] = (short)b;
            pk[j] = (unsigned)s | ((unsigned)(d & 255) << 16);
            rk[j] = atomicAdd(&cnt[b], 1);
        } else bk[j] = -1;
    }
    __syncthreads();
    for (int i = t; i < NBKT; i += 256)
        gbase[i] = atomicAdd(&gfill[i], cnt[i]);
    __syncthreads();
#pragma unroll
    for (int j = 0; j < 16; ++j) {
        if (bk[j] >= 0) {
            int pos = gbase[bk[j]] + rk[j];
            if (pos < BCAP) staging[(size_t)bk[j] * BCAP + pos] = pk[j];
        }
    }
}

// Pass B: per bucket -> exact CSR (self-loop first, then edges grouped by
// src>>13 for L2 phase-locality in k_agg), dinv, and dinv-prescaled h16 rows.
__global__ __launch_bounds__(256) void k_binB(const unsigned* __restrict__ staging,
                                              const int* __restrict__ gfill,
                                              const float* __restrict__ h,
                                              int* __restrict__ ptr,
                                              float* __restrict__ dinv,
                                              _Float16* __restrict__ h16,
                                              int* __restrict__ esrc) {
    __shared__ unsigned se[BCAP];
    __shared__ int lcnt[256];
    __shared__ int lscan[256];
    __shared__ int cur[256];
    __shared__ float sdinv[256];
    __shared__ int s_cb;
    int b = blockIdx.x, t = threadIdx.x;
    int nbase = b * 256;
    int nn = min(256, N_NODES - nbase);
    int cnt = min(gfill[b], BCAP);
    // CSR base for this bucket: sum_{i<b} (edges_i + 256 self-loops)
    if (t < 64) {
        int acc = 0;
        for (int i = t; i < b; i += 64) acc += min(gfill[i], BCAP) + 256;
#pragma unroll
        for (int off = 32; off > 0; off >>= 1) acc += __shfl_down(acc, off);
        if (t == 0) s_cb = acc;
    }
    lcnt[t] = 0;
    __syncthreads();
    int cb = s_cb;
    const unsigned* st = staging + (size_t)b * BCAP;
    for (int i = t; i < cnt; i += 256) {
        unsigned p = st[i];
        se[i] = p;
        atomicAdd(&lcnt[p >> 16], 1);
    }
    __syncthreads();
    int v = lcnt[t];
    lscan[t] = v;
    __syncthreads();
    for (int off = 1; off < 256; off <<= 1) {
        int x = (t >= off) ? lscan[t - off] : 0;
        __syncthreads(); lscan[t] += x; __syncthreads();
    }
    int segstart = cb + (lscan[t] - v) + t;
    float dv = rsqrtf((float)(v + 1));
    if (t < nn) {
        int node = nbase + t;
        ptr[node] = segstart;
        dinv[node] = dv;
        sdinv[t] = dv;
        esrc[segstart] = node;             // self-loop entry first
        cur[t] = segstart + 1;
    }
    __syncthreads();
    for (int g = 0; g < 7; ++g) {          // group by src chunk (2.1MB of h16)
        for (int i = t; i < cnt; i += 256) {
            unsigned p = se[i];
            int s = (int)(p & 0xffffu);
            if ((s >> 13) == g) {
                int pos = atomicAdd(&cur[p >> 16], 1);
                esrc[pos] = s;
            }
        }
        __syncthreads();
    }
    // h16[node] = f16(h[node] * dinv[node]) — 2 rows per iteration, coalesced
    int half = t >> 7;
    int col = t & 127;
    for (int r = half; r < nn; r += 2) {
        int node = nbase + r;
        h16[(size_t)node * 128 + col] = (_Float16)(h[(size_t)node * 128 + col] * sdinv[r]);
    }
}

// one wave per node: u[v] = f16( dinv[v] * sum(h16[src]) )   (8-deep MLP)
__global__ __launch_bounds__(256) void k_agg(const _Float16* __restrict__ h16,
                                             const int* __restrict__ ptr,
                                             const int* __restrict__ esrc,
                                             const float* __restrict__ dinv,
                                             _Float16* __restrict__ u) {
    int wid = (blockIdx.x * 256 + threadIdx.x) >> 6;
    int lane = threadIdx.x & 63;
    if (wid >= N_NODES) return;
    int p0 = ptr[wid];
    int p1 = (wid + 1 < N_NODES) ? ptr[wid + 1] : TOT;
    float a0 = 0.f, a1 = 0.f;
    for (int base = p0; base < p1; base += 64) {
        int cnt = p1 - base; if (cnt > 64) cnt = 64;
        int idx = 0;
        if (lane < cnt) idx = esrc[base + lane];
        int j = 0;
        for (; j + 8 <= cnt; j += 8) {
            int s0 = __shfl(idx, j),     s1 = __shfl(idx, j + 1);
            int s2 = __shfl(idx, j + 2), s3 = __shfl(idx, j + 3);
            int s4 = __shfl(idx, j + 4), s5 = __shfl(idx, j + 5);
            int s6 = __shfl(idx, j + 6), s7 = __shfl(idx, j + 7);
            half2v u0 = *(const half2v*)(h16 + (size_t)s0 * 128 + lane * 2);
            half2v u1 = *(const half2v*)(h16 + (size_t)s1 * 128 + lane * 2);
            half2v u2 = *(const half2v*)(h16 + (size_t)s2 * 128 + lane * 2);
            half2v u3 = *(const half2v*)(h16 + (size_t)s3 * 128 + lane * 2);
            half2v u4 = *(const half2v*)(h16 + (size_t)s4 * 128 + lane * 2);
            half2v u5 = *(const half2v*)(h16 + (size_t)s5 * 128 + lane * 2);
            half2v u6 = *(const half2v*)(h16 + (size_t)s6 * 128 + lane * 2);
            half2v u7 = *(const half2v*)(h16 + (size_t)s7 * 128 + lane * 2);
            a0 += (float)u0[0] + (float)u1[0] + (float)u2[0] + (float)u3[0]
                + (float)u4[0] + (float)u5[0] + (float)u6[0] + (float)u7[0];
            a1 += (float)u0[1] + (float)u1[1] + (float)u2[1] + (float)u3[1]
                + (float)u4[1] + (float)u5[1] + (float)u6[1] + (float)u7[1];
        }
        for (; j + 4 <= cnt; j += 4) {
            int s0 = __shfl(idx, j),     s1 = __shfl(idx, j + 1);
            int s2 = __shfl(idx, j + 2), s3 = __shfl(idx, j + 3);
            half2v u0 = *(const half2v*)(h16 + (size_t)s0 * 128 + lane * 2);
            half2v u1 = *(const half2v*)(h16 + (size_t)s1 * 128 + lane * 2);
            half2v u2 = *(const half2v*)(h16 + (size_t)s2 * 128 + lane * 2);
            half2v u3 = *(const half2v*)(h16 + (size_t)s3 * 128 + lane * 2);
            a0 += (float)u0[0] + (float)u1[0] + (float)u2[0] + (float)u3[0];
            a1 += (float)u0[1] + (float)u1[1] + (float)u2[1] + (float)u3[1];
        }
        for (; j < cnt; ++j) {
            int s = __shfl(idx, j);
            half2v uu = *(const half2v*)(h16 + (size_t)s * 128 + lane * 2);
            a0 += (float)uu[0]; a1 += (float)uu[1];
        }
    }
    float sc = dinv[wid];
    half2v o; o[0] = (_Float16)(a0 * sc); o[1] = (_Float16)(a1 * sc);
    *(half2v*)(u + (size_t)wid * 128 + lane * 2) = o;
}

// fused double GEMM: out = relu(u@Wg + b_gcn) @ Wf + b_fc
// relu'd 16x128 tile round-trips through LDS (MFMA C-layout -> A-layout).
__global__ __launch_bounds__(256) void k_gemmF(const _Float16* __restrict__ u,
                                               const _Float16* __restrict__ W1,
                                               const _Float16* __restrict__ W2,
                                               const float* __restrict__ bg,
                                               const float* __restrict__ bfc,
                                               float* __restrict__ out) {
    __shared__ _Float16 zt[4][16 * 128];   // 16KB
    int wave = threadIdx.x >> 6;
    int lane = threadIdx.x & 63;
    int rowbase = (blockIdx.x * 4 + wave) * 16;
    if (rowbase > N_NODES - 16) rowbase = N_NODES - 16;  // keep all waves alive (dup rows benign)
    int quad = lane >> 4;
    int l15 = lane & 15;
    int mr = rowbase + l15;
    half8 a[4];
#pragma unroll
    for (int kk = 0; kk < 4; ++kk)
        a[kk] = *(const half8*)(u + (size_t)mr * 128 + kk * 32 + quad * 8);
    _Float16* z = zt[wave];
#pragma unroll
    for (int nt = 0; nt < 8; ++nt) {
        floatx4 acc = {0.f, 0.f, 0.f, 0.f};
        int n = nt * 16 + l15;
#pragma unroll
        for (int kk = 0; kk < 4; ++kk) {
            half8 bb = *(const half8*)(W1 + n * 128 + kk * 32 + quad * 8);
            acc = __builtin_amdgcn_mfma_f32_16x16x32_f16(a[kk], bb, acc, 0, 0, 0);
        }
        float bias = bg[n];
#pragma unroll
        for (int i = 0; i < 4; ++i) {
            int row = quad * 4 + i;                      // C-layout: col=l15, row=quad*4+i
            z[row * 128 + n] = (_Float16)fmaxf(acc[i] + bias, 0.f);
        }
    }
    __syncthreads();
    half8 a2[4];
#pragma unroll
    for (int kk = 0; kk < 4; ++kk)                       // A-layout read-back
        a2[kk] = *(const half8*)(z + l15 * 128 + kk * 32 + quad * 8);
#pragma unroll
    for (int mt = 0; mt < 4; ++mt) {
        floatx4 acc = {0.f, 0.f, 0.f, 0.f};
        int n = mt * 16 + l15;
#pragma unroll
        for (int kk = 0; kk < 4; ++kk) {
            half8 bb = *(const half8*)(W2 + n * 128 + kk * 32 + quad * 8);
            acc = __builtin_amdgcn_mfma_f32_16x16x32_f16(a2[kk], bb, acc, 0, 0, 0);
        }
        float bias = bfc[n];
#pragma unroll
        for (int i = 0; i < 4; ++i) {
            int row = rowbase + quad * 4 + i;
            out[(size_t)row * 64 + n] = acc[i] + bias;   // dup waves write identical values
        }
    }
}

extern "C" void kernel_launch(void* const* d_in, const int* in_sizes, int n_in,
                              void* d_out, int out_size, void* d_ws, size_t ws_size,
                              hipStream_t stream) {
    (void)in_sizes; (void)n_in; (void)out_size; (void)ws_size;
    const float* h  = (const float*)d_in[0];
    const int*   ei = (const int*)d_in[1];
    const float* Wg = (const float*)d_in[2];
    const float* bg = (const float*)d_in[3];
    const float* Wf = (const float*)d_in[4];
    const float* bf = (const float*)d_in[5];
    float* out = (float*)d_out;

    char* ws = (char*)d_ws;
    int*      ptr   = (int*)(ws + O_PTR);
    int*      gfill = (int*)(ws + O_GF);
    int*      flags = (int*)(ws + O_FLAG);
    float*    dinv  = (float*)(ws + O_DINV);
    int*      esrc  = (int*)(ws + O_ESRC);
    _Float16* W1    = (_Float16*)(ws + O_W1);
    _Float16* W2    = (_Float16*)(ws + O_W2);
    _Float16* u     = (_Float16*)(ws + O_U);
    _Float16* h16   = (_Float16*)(ws + O_H16);
    unsigned* staging = (unsigned*)(ws + O_U);   // aliased; dead before k_agg writes u

    k_prep<<<64, 256, 0, stream>>>(Wg, Wf, (const unsigned*)ei, gfill, W1, W2, flags);
    k_binA<<<NBKT, 256, 0, stream>>>(ei, flags, gfill, staging);
    k_binB<<<NBKT, 256, 0, stream>>>(staging, gfill, h, ptr, dinv, h16, esrc);
    k_agg<<<(N_NODES + 3) / 4, 256, 0, stream>>>(h16, ptr, esrc, dinv, u);
    k_gemmF<<<(N_NODES + 63) / 64, 256, 0, stream>>>(u, W1, W2, bg, bf, out);
}

// Round 7
// 176.512 us; speedup vs baseline: 1.0248x; 1.0248x over previous
//
#include <hip/hip_runtime.h>

#define N_NODES 50000
#define N_EDGES 800000
#define TOT (N_EDGES + N_NODES)
#define NBKT 196          // dest buckets of 256 nodes
#define BCAP 6144         // staging capacity per bucket (mean 4096 + 32 sigma)

typedef __attribute__((ext_vector_type(4))) float floatx4;
typedef __attribute__((ext_vector_type(8))) _Float16 half8;
typedef __attribute__((ext_vector_type(2))) _Float16 half2v;

// ---- workspace layout (bytes) ----
#define O_PTR   0UL          // int[N]
#define O_GF    200192UL     // int[NBKT]
#define O_DINV  201472UL     // float[N]
#define O_ESRC  401664UL     // int[TOT] 3.4MB
#define O_W1    3801856UL    // f16[128*128] (transposed [n][k])
#define O_W2    3834624UL    // f16[64*128]  (transposed [n][k])
#define O_U     3851008UL    // f16[N*128] aggregated rows; ALIASED: u32 staging[NBKT*BCAP]=4.8MB (dead before k_agg)
#define O_H16   16651008UL   // f16[N*128] dinv-prescaled h
// end: 29451008 bytes (<= 29.9MB proven footprint)

// Pass A: coarse-bin edges by dest>>8 into per-bucket staging runs.
// Index width (int32 vs int64) probed per-block from the first 64 odd words.
__global__ __launch_bounds__(256) void k_binA(const int* __restrict__ ei,
                                              int* __restrict__ gfill,
                                              unsigned* __restrict__ staging) {
    __shared__ int cnt[NBKT];
    __shared__ int gbase[NBKT];
    __shared__ int s_i64;
    int t = threadIdx.x;
    if (t < 64) {                                  // wave 0: int64 probe
        unsigned w = ((const unsigned*)ei)[2 * t + 1];
        unsigned long long m = __ballot(w == 0u);
        if (t == 0) s_i64 = (__popcll(m) >= 60) ? 1 : 0;
    }
    for (int i = t; i < NBKT; i += 256) cnt[i] = 0;
    __syncthreads();
    bool i64 = s_i64 != 0;
    int ebase = blockIdx.x * 4096;
    unsigned pk[16]; int rk[16]; short bk[16];
#pragma unroll
    for (int j = 0; j < 16; ++j) {
        int e = ebase + j * 256 + t;
        if (e < N_EDGES) {
            int s, d;
            if (i64) { s = ei[2 * e]; d = ei[2 * (N_EDGES + e)]; }
            else     { s = ei[e];     d = ei[N_EDGES + e]; }
            int b = d >> 8;
            bk[j] = (short)b;
            pk[j] = (unsigned)s | ((unsigned)(d & 255) << 16);
            rk[j] = atomicAdd(&cnt[b], 1);
        } else bk[j] = -1;
    }
    __syncthreads();
    for (int i = t; i < NBKT; i += 256)
        gbase[i] = atomicAdd(&gfill[i], cnt[i]);
    __syncthreads();
#pragma unroll
    for (int j = 0; j < 16; ++j) {
        if (bk[j] >= 0) {
            int pos = gbase[bk[j]] + rk[j];
            if (pos < BCAP) staging[(size_t)bk[j] * BCAP + pos] = pk[j];
        }
    }
}

// Pass B: per bucket -> exact CSR (self-loop first), dinv, dinv-prescaled h16.
// Blocks 0..95 additionally transpose one 256-elem weight chunk to f16.
__global__ __launch_bounds__(256) void k_binB(const unsigned* __restrict__ staging,
                                              const int* __restrict__ gfill,
                                              const float* __restrict__ h,
                                              const float* __restrict__ Wg,
                                              const float* __restrict__ Wf,
                                              int* __restrict__ ptr,
                                              float* __restrict__ dinv,
                                              _Float16* __restrict__ h16,
                                              _Float16* __restrict__ W1,
                                              _Float16* __restrict__ W2,
                                              int* __restrict__ esrc) {
    __shared__ unsigned se[BCAP];
    __shared__ int lcnt[256];
    __shared__ int lscan[256];
    __shared__ int cur[256];
    __shared__ float sdinv[256];
    __shared__ int s_cb;
    int b = blockIdx.x, t = threadIdx.x;
    // weight transpose side-job (consumed only by k_gemmF, which runs later)
    if (b < 64) {
        int i = b * 256 + t;                       // W1: 16384 elems
        int n = i >> 7, k = i & 127;
        W1[i] = (_Float16)Wg[k * 128 + n];
    } else if (b < 96) {
        int i = (b - 64) * 256 + t;                // W2: 8192 elems
        int n = i >> 7, k = i & 127;
        W2[i] = (_Float16)Wf[k * 64 + n];
    }
    int nbase = b * 256;
    int nn = min(256, N_NODES - nbase);
    int cnt = min(gfill[b], BCAP);
    // CSR base for this bucket: sum_{i<b} (edges_i + 256 self-loops)
    if (t < 64) {
        int acc = 0;
        for (int i = t; i < b; i += 64) acc += min(gfill[i], BCAP) + 256;
#pragma unroll
        for (int off = 32; off > 0; off >>= 1) acc += __shfl_down(acc, off);
        if (t == 0) s_cb = acc;
    }
    lcnt[t] = 0;
    __syncthreads();
    int cb = s_cb;
    const unsigned* st = staging + (size_t)b * BCAP;
    for (int i = t; i < cnt; i += 256) {
        unsigned p = st[i];
        se[i] = p;
        atomicAdd(&lcnt[p >> 16], 1);
    }
    __syncthreads();
    int v = lcnt[t];
    lscan[t] = v;
    __syncthreads();
    for (int off = 1; off < 256; off <<= 1) {
        int x = (t >= off) ? lscan[t - off] : 0;
        __syncthreads(); lscan[t] += x; __syncthreads();
    }
    int segstart = cb + (lscan[t] - v) + t;
    float dv = rsqrtf((float)(v + 1));
    if (t < nn) {
        int node = nbase + t;
        ptr[node] = segstart;
        dinv[node] = dv;
        sdinv[t] = dv;
        esrc[segstart] = node;             // self-loop entry first
        cur[t] = segstart + 1;
    }
    __syncthreads();
    for (int i = t; i < cnt; i += 256) {   // single-pass scatter
        unsigned p = se[i];
        int pos = atomicAdd(&cur[p >> 16], 1);
        esrc[pos] = (int)(p & 0xffffu);
    }
    // h16[node] = f16(h[node] * dinv[node]) — 2 rows per iteration, coalesced
    int half = t >> 7;
    int col = t & 127;
    for (int r = half; r < nn; r += 2) {
        int node = nbase + r;
        h16[(size_t)node * 128 + col] = (_Float16)(h[(size_t)node * 128 + col] * sdinv[r]);
    }
}

// one wave per node: u[v] = f16( dinv[v] * sum(h16[src]) )   (8-deep MLP)
__global__ __launch_bounds__(256) void k_agg(const _Float16* __restrict__ h16,
                                             const int* __restrict__ ptr,
                                             const int* __restrict__ esrc,
                                             const float* __restrict__ dinv,
                                             _Float16* __restrict__ u) {
    int wid = (blockIdx.x * 256 + threadIdx.x) >> 6;
    int lane = threadIdx.x & 63;
    if (wid >= N_NODES) return;
    int p0 = ptr[wid];
    int p1 = (wid + 1 < N_NODES) ? ptr[wid + 1] : TOT;
    float a0 = 0.f, a1 = 0.f;
    for (int base = p0; base < p1; base += 64) {
        int cnt = p1 - base; if (cnt > 64) cnt = 64;
        int idx = 0;
        if (lane < cnt) idx = esrc[base + lane];
        int j = 0;
        for (; j + 8 <= cnt; j += 8) {
            int s0 = __shfl(idx, j),     s1 = __shfl(idx, j + 1);
            int s2 = __shfl(idx, j + 2), s3 = __shfl(idx, j + 3);
            int s4 = __shfl(idx, j + 4), s5 = __shfl(idx, j + 5);
            int s6 = __shfl(idx, j + 6), s7 = __shfl(idx, j + 7);
            half2v u0 = *(const half2v*)(h16 + (size_t)s0 * 128 + lane * 2);
            half2v u1 = *(const half2v*)(h16 + (size_t)s1 * 128 + lane * 2);
            half2v u2 = *(const half2v*)(h16 + (size_t)s2 * 128 + lane * 2);
            half2v u3 = *(const half2v*)(h16 + (size_t)s3 * 128 + lane * 2);
            half2v u4 = *(const half2v*)(h16 + (size_t)s4 * 128 + lane * 2);
            half2v u5 = *(const half2v*)(h16 + (size_t)s5 * 128 + lane * 2);
            half2v u6 = *(const half2v*)(h16 + (size_t)s6 * 128 + lane * 2);
            half2v u7 = *(const half2v*)(h16 + (size_t)s7 * 128 + lane * 2);
            a0 += (float)u0[0] + (float)u1[0] + (float)u2[0] + (float)u3[0]
                + (float)u4[0] + (float)u5[0] + (float)u6[0] + (float)u7[0];
            a1 += (float)u0[1] + (float)u1[1] + (float)u2[1] + (float)u3[1]
                + (float)u4[1] + (float)u5[1] + (float)u6[1] + (float)u7[1];
        }
        for (; j + 4 <= cnt; j += 4) {
            int s0 = __shfl(idx, j),     s1 = __shfl(idx, j + 1);
            int s2 = __shfl(idx, j + 2), s3 = __shfl(idx, j + 3);
            half2v u0 = *(const half2v*)(h16 + (size_t)s0 * 128 + lane * 2);
            half2v u1 = *(const half2v*)(h16 + (size_t)s1 * 128 + lane * 2);
            half2v u2 = *(const half2v*)(h16 + (size_t)s2 * 128 + lane * 2);
            half2v u3 = *(const half2v*)(h16 + (size_t)s3 * 128 + lane * 2);
            a0 += (float)u0[0] + (float)u1[0] + (float)u2[0] + (float)u3[0];
            a1 += (float)u0[1] + (float)u1[1] + (float)u2[1] + (float)u3[1];
        }
        for (; j < cnt; ++j) {
            int s = __shfl(idx, j);
            half2v uu = *(const half2v*)(h16 + (size_t)s * 128 + lane * 2);
            a0 += (float)uu[0]; a1 += (float)uu[1];
        }
    }
    float sc = dinv[wid];
    half2v o; o[0] = (_Float16)(a0 * sc); o[1] = (_Float16)(a1 * sc);
    *(half2v*)(u + (size_t)wid * 128 + lane * 2) = o;
}

// fused double GEMM: out = relu(u@Wg + b_gcn) @ Wf + b_fc
// relu'd 16x128 tile round-trips through LDS (MFMA C-layout -> A-layout).
__global__ __launch_bounds__(256) void k_gemmF(const _Float16* __restrict__ u,
                                               const _Float16* __restrict__ W1,
                                               const _Float16* __restrict__ W2,
                                               const float* __restrict__ bg,
                                               const float* __restrict__ bfc,
                                               float* __restrict__ out) {
    __shared__ _Float16 zt[4][16 * 128];   // 16KB
    int wave = threadIdx.x >> 6;
    int lane = threadIdx.x & 63;
    int rowbase = (blockIdx.x * 4 + wave) * 16;
    if (rowbase > N_NODES - 16) rowbase = N_NODES - 16;  // keep all waves alive (dup rows benign)
    int quad = lane >> 4;
    int l15 = lane & 15;
    int mr = rowbase + l15;
    half8 a[4];
#pragma unroll
    for (int kk = 0; kk < 4; ++kk)
        a[kk] = *(const half8*)(u + (size_t)mr * 128 + kk * 32 + quad * 8);
    _Float16* z = zt[wave];
#pragma unroll
    for (int nt = 0; nt < 8; ++nt) {
        floatx4 acc = {0.f, 0.f, 0.f, 0.f};
        int n = nt * 16 + l15;
#pragma unroll
        for (int kk = 0; kk < 4; ++kk) {
            half8 bb = *(const half8*)(W1 + n * 128 + kk * 32 + quad * 8);
            acc = __builtin_amdgcn_mfma_f32_16x16x32_f16(a[kk], bb, acc, 0, 0, 0);
        }
        float bias = bg[n];
#pragma unroll
        for (int i = 0; i < 4; ++i) {
            int row = quad * 4 + i;                      // C-layout: col=l15, row=quad*4+i
            z[row * 128 + n] = (_Float16)fmaxf(acc[i] + bias, 0.f);
        }
    }
    __syncthreads();
    half8 a2[4];
#pragma unroll
    for (int kk = 0; kk < 4; ++kk)                       // A-layout read-back
        a2[kk] = *(const half8*)(z + l15 * 128 + kk * 32 + quad * 8);
#pragma unroll
    for (int mt = 0; mt < 4; ++mt) {
        floatx4 acc = {0.f, 0.f, 0.f, 0.f};
        int n = mt * 16 + l15;
#pragma unroll
        for (int kk = 0; kk < 4; ++kk) {
            half8 bb = *(const half8*)(W2 + n * 128 + kk * 32 + quad * 8);
            acc = __builtin_amdgcn_mfma_f32_16x16x32_f16(a2[kk], bb, acc, 0, 0, 0);
        }
        float bias = bfc[n];
#pragma unroll
        for (int i = 0; i < 4; ++i) {
            int row = rowbase + quad * 4 + i;
            out[(size_t)row * 64 + n] = acc[i] + bias;   // dup waves write identical values
        }
    }
}

extern "C" void kernel_launch(void* const* d_in, const int* in_sizes, int n_in,
                              void* d_out, int out_size, void* d_ws, size_t ws_size,
                              hipStream_t stream) {
    (void)in_sizes; (void)n_in; (void)out_size; (void)ws_size;
    const float* h  = (const float*)d_in[0];
    const int*   ei = (const int*)d_in[1];
    const float* Wg = (const float*)d_in[2];
    const float* bg = (const float*)d_in[3];
    const float* Wf = (const float*)d_in[4];
    const float* bf = (const float*)d_in[5];
    float* out = (float*)d_out;

    char* ws = (char*)d_ws;
    int*      ptr   = (int*)(ws + O_PTR);
    int*      gfill = (int*)(ws + O_GF);
    float*    dinv  = (float*)(ws + O_DINV);
    int*      esrc  = (int*)(ws + O_ESRC);
    _Float16* W1    = (_Float16*)(ws + O_W1);
    _Float16* W2    = (_Float16*)(ws + O_W2);
    _Float16* u     = (_Float16*)(ws + O_U);
    _Float16* h16   = (_Float16*)(ws + O_H16);
    unsigned* staging = (unsigned*)(ws + O_U);   // aliased; dead before k_agg writes u

    hipMemsetAsync(gfill, 0, NBKT * sizeof(int), stream);
    k_binA<<<NBKT, 256, 0, stream>>>(ei, gfill, staging);
    k_binB<<<NBKT, 256, 0, stream>>>(staging, gfill, h, Wg, Wf,
                                     ptr, dinv, h16, W1, W2, esrc);
    k_agg<<<(N_NODES + 3) / 4, 256, 0, stream>>>(h16, ptr, esrc, dinv, u);
    k_gemmF<<<(N_NODES + 63) / 64, 256, 0, stream>>>(u, W1, W2, bg, bf, out);
}

// Round 8
// 155.132 us; speedup vs baseline: 1.1660x; 1.1378x over previous
//
#include <hip/hip_runtime.h>

#define N_NODES 50000
#define N_EDGES 800000
#define NBKT 196          // dest buckets of 256 nodes
#define BCAP 6144         // staging capacity per bucket (mean 4096 + 32 sigma)

typedef __attribute__((ext_vector_type(4))) float floatx4;
typedef __attribute__((ext_vector_type(8))) _Float16 half8;
typedef __attribute__((ext_vector_type(2))) _Float16 half2v;

// ---- workspace layout (bytes) ----
#define O_PTR   0UL          // int[N] (edge-only CSR starts)
#define O_GF    200192UL     // int[NBKT]
#define O_DINV  201472UL     // float[N]
#define O_ESRC  401664UL     // int[N_EDGES] 3.2MB
#define O_W1    3801856UL    // f16[128*128] (transposed [n][k])
#define O_W2    3834624UL    // f16[64*128]  (transposed [n][k])
#define O_STG   3851008UL    // u32 staging[NBKT*BCAP] = 4.8MB
#define O_H16   16651008UL   // f16[N*128] dinv-prescaled h
// end: 29451008 bytes (<= 29.9MB proven footprint)

// Pass A: coarse-bin edges by dest>>8 into per-bucket staging runs.
// Index width (int32 vs int64) probed per-block from the first 64 odd words.
__global__ __launch_bounds__(256) void k_binA(const int* __restrict__ ei,
                                              int* __restrict__ gfill,
                                              unsigned* __restrict__ staging) {
    __shared__ int cnt[NBKT];
    __shared__ int gbase[NBKT];
    __shared__ int s_i64;
    int t = threadIdx.x;
    if (t < 64) {                                  // wave 0: int64 probe
        unsigned w = ((const unsigned*)ei)[2 * t + 1];
        unsigned long long m = __ballot(w == 0u);
        if (t == 0) s_i64 = (__popcll(m) >= 60) ? 1 : 0;
    }
    for (int i = t; i < NBKT; i += 256) cnt[i] = 0;
    __syncthreads();
    bool i64 = s_i64 != 0;
    int e0 = blockIdx.x * 4096 + t * 16;           // 16 edges per thread
    int sv[16], dvv[16];
    if (i64) {
        const int4* ps = (const int4*)(ei) + (e0 >> 1);
        const int4* pd = (const int4*)(ei + 2 * (size_t)N_EDGES) + (e0 >> 1);
#pragma unroll
        for (int g = 0; g < 8; ++g) {
            if (e0 + 2 * g < N_EDGES) {
                int4 s4 = ps[g], d4 = pd[g];
                sv[2 * g] = s4.x; sv[2 * g + 1] = s4.z;
                dvv[2 * g] = d4.x; dvv[2 * g + 1] = d4.z;
            } else { dvv[2 * g] = -1; dvv[2 * g + 1] = -1; }
        }
    } else {
        const int4* ps = (const int4*)(ei) + (e0 >> 2);
        const int4* pd = (const int4*)(ei + (size_t)N_EDGES) + (e0 >> 2);
#pragma unroll
        for (int g = 0; g < 4; ++g) {
            if (e0 + 4 * g < N_EDGES) {
                int4 s4 = ps[g], d4 = pd[g];
                sv[4 * g] = s4.x; sv[4 * g + 1] = s4.y; sv[4 * g + 2] = s4.z; sv[4 * g + 3] = s4.w;
                dvv[4 * g] = d4.x; dvv[4 * g + 1] = d4.y; dvv[4 * g + 2] = d4.z; dvv[4 * g + 3] = d4.w;
            } else { dvv[4 * g] = -1; dvv[4 * g + 1] = -1; dvv[4 * g + 2] = -1; dvv[4 * g + 3] = -1; }
        }
    }
    unsigned pk[16]; int rk[16]; short bk[16];
#pragma unroll
    for (int j = 0; j < 16; ++j) {
        int d = dvv[j];
        if (d >= 0 && e0 + j < N_EDGES) {
            int b = d >> 8;
            bk[j] = (short)b;
            pk[j] = (unsigned)sv[j] | ((unsigned)(d & 255) << 16);
            rk[j] = atomicAdd(&cnt[b], 1);
        } else bk[j] = -1;
    }
    __syncthreads();
    for (int i = t; i < NBKT; i += 256)
        gbase[i] = atomicAdd(&gfill[i], cnt[i]);
    __syncthreads();
#pragma unroll
    for (int j = 0; j < 16; ++j) {
        if (bk[j] >= 0) {
            int pos = gbase[bk[j]] + rk[j];
            if (pos < BCAP) staging[(size_t)bk[j] * BCAP + pos] = pk[j];
        }
    }
}

// Pass B: per bucket -> edge-only CSR, dinv, dinv-prescaled h16.
// Blocks 0..95 additionally transpose one 256-elem weight chunk to f16.
__global__ __launch_bounds__(256) void k_binB(const unsigned* __restrict__ staging,
                                              const int* __restrict__ gfill,
                                              const float* __restrict__ h,
                                              const float* __restrict__ Wg,
                                              const float* __restrict__ Wf,
                                              int* __restrict__ ptr,
                                              float* __restrict__ dinv,
                                              _Float16* __restrict__ h16,
                                              _Float16* __restrict__ W1,
                                              _Float16* __restrict__ W2,
                                              int* __restrict__ esrc) {
    __shared__ unsigned se[BCAP];
    __shared__ int lcnt[256];
    __shared__ int lscan[256];
    __shared__ int cur[256];
    __shared__ float sdinv[256];
    __shared__ int s_cb;
    int b = blockIdx.x, t = threadIdx.x;
    if (b < 64) {
        int i = b * 256 + t;                       // W1: 16384 elems
        int n = i >> 7, k = i & 127;
        W1[i] = (_Float16)Wg[k * 128 + n];
    } else if (b < 96) {
        int i = (b - 64) * 256 + t;                // W2: 8192 elems
        int n = i >> 7, k = i & 127;
        W2[i] = (_Float16)Wf[k * 64 + n];
    }
    int nbase = b * 256;
    int nn = min(256, N_NODES - nbase);
    int cnt = min(gfill[b], BCAP);
    if (t < 64) {                                  // edge-CSR base: sum_{i<b} edges_i
        int acc = 0;
        for (int i = t; i < b; i += 64) acc += min(gfill[i], BCAP);
#pragma unroll
        for (int off = 32; off > 0; off >>= 1) acc += __shfl_down(acc, off);
        if (t == 0) s_cb = acc;
    }
    lcnt[t] = 0;
    __syncthreads();
    int cb = s_cb;
    const unsigned* st = staging + (size_t)b * BCAP;
    for (int i = t; i < cnt; i += 256) {
        unsigned p = st[i];
        se[i] = p;
        atomicAdd(&lcnt[p >> 16], 1);
    }
    __syncthreads();
    int v = lcnt[t];
    lscan[t] = v;
    __syncthreads();
    for (int off = 1; off < 256; off <<= 1) {
        int x = (t >= off) ? lscan[t - off] : 0;
        __syncthreads(); lscan[t] += x; __syncthreads();
    }
    int segstart = cb + (lscan[t] - v);
    float dv = rsqrtf((float)(v + 1));             // +1 = self-loop (analytic in k_aggF)
    if (t < nn) {
        int node = nbase + t;
        ptr[node] = segstart;
        dinv[node] = dv;
        sdinv[t] = dv;
        cur[t] = segstart;
    }
    __syncthreads();
    for (int i = t; i < cnt; i += 256) {           // single-pass scatter
        unsigned p = se[i];
        int pos = atomicAdd(&cur[p >> 16], 1);
        esrc[pos] = (int)(p & 0xffffu);
    }
    int half = t >> 7;
    int col = t & 127;
    for (int r = half; r < nn; r += 2) {           // h16 = f16(h * dinv), coalesced
        int node = nbase + r;
        h16[(size_t)node * 128 + col] = (_Float16)(h[(size_t)node * 128 + col] * sdinv[r]);
    }
}

// Fused aggregate + double GEMM. Block = 16 consecutive nodes (grid 3125).
__global__ __launch_bounds__(256) void k_aggF(const _Float16* __restrict__ h16,
                                              const int* __restrict__ ptr,
                                              const int* __restrict__ esrc,
                                              const float* __restrict__ dinv,
                                              const _Float16* __restrict__ W1,
                                              const _Float16* __restrict__ W2,
                                              const float* __restrict__ bg,
                                              const float* __restrict__ bfc,
                                              float* __restrict__ out) {
    __shared__ _Float16 ut[16 * 128];
    __shared__ _Float16 z[16 * 128];
    int wave = threadIdx.x >> 6;
    int lane = threadIdx.x & 63;
    int nb = blockIdx.x * 16;
    for (int q = 0; q < 4; ++q) {
        int node = nb + wave * 4 + q;
        int p0 = ptr[node];
        int p1 = (node + 1 < N_NODES) ? ptr[node + 1] : N_EDGES;
        half2v us = *(const half2v*)(h16 + (size_t)node * 128 + lane * 2);
        float a0 = (float)us[0], a1 = (float)us[1];           // self-loop
        for (int base = p0; base < p1; base += 64) {
            int cnt = p1 - base; if (cnt > 64) cnt = 64;
            int idx = 0;
            if (lane < cnt) idx = esrc[base + lane];
            int j = 0;
            for (; j + 8 <= cnt; j += 8) {
                int s0 = __shfl(idx, j),     s1 = __shfl(idx, j + 1);
                int s2 = __shfl(idx, j + 2), s3 = __shfl(idx, j + 3);
                int s4 = __shfl(idx, j + 4), s5 = __shfl(idx, j + 5);
                int s6 = __shfl(idx, j + 6), s7 = __shfl(idx, j + 7);
                half2v u0 = *(const half2v*)(h16 + (size_t)s0 * 128 + lane * 2);
                half2v u1 = *(const half2v*)(h16 + (size_t)s1 * 128 + lane * 2);
                half2v u2 = *(const half2v*)(h16 + (size_t)s2 * 128 + lane * 2);
                half2v u3 = *(const half2v*)(h16 + (size_t)s3 * 128 + lane * 2);
                half2v u4 = *(const half2v*)(h16 + (size_t)s4 * 128 + lane * 2);
                half2v u5 = *(const half2v*)(h16 + (size_t)s5 * 128 + lane * 2);
                half2v u6 = *(const half2v*)(h16 + (size_t)s6 * 128 + lane * 2);
                half2v u7 = *(const half2v*)(h16 + (size_t)s7 * 128 + lane * 2);
                a0 += (float)u0[0] + (float)u1[0] + (float)u2[0] + (float)u3[0]
                    + (float)u4[0] + (float)u5[0] + (float)u6[0] + (float)u7[0];
                a1 += (float)u0[1] + (float)u1[1] + (float)u2[1] + (float)u3[1]
                    + (float)u4[1] + (float)u5[1] + (float)u6[1] + (float)u7[1];
            }
            for (; j + 4 <= cnt; j += 4) {
                int s0 = __shfl(idx, j),     s1 = __shfl(idx, j + 1);
                int s2 = __shfl(idx, j + 2), s3 = __shfl(idx, j + 3);
                half2v u0 = *(const half2v*)(h16 + (size_t)s0 * 128 + lane * 2);
                half2v u1 = *(const half2v*)(h16 + (size_t)s1 * 128 + lane * 2);
                half2v u2 = *(const half2v*)(h16 + (size_t)s2 * 128 + lane * 2);
                half2v u3 = *(const half2v*)(h16 + (size_t)s3 * 128 + lane * 2);
                a0 += (float)u0[0] + (float)u1[0] + (float)u2[0] + (float)u3[0];
                a1 += (float)u0[1] + (float)u1[1] + (float)u2[1] + (float)u3[1];
            }
            for (; j < cnt; ++j) {
                int s = __shfl(idx, j);
                half2v uu = *(const half2v*)(h16 + (size_t)s * 128 + lane * 2);
                a0 += (float)uu[0]; a1 += (float)uu[1];
            }
        }
        float sc = dinv[node];
        int r = wave * 4 + q;
        ut[r * 128 + lane * 2]     = (_Float16)(a0 * sc);
        ut[r * 128 + lane * 2 + 1] = (_Float16)(a1 * sc);
    }
    __syncthreads();
    int quad = lane >> 4, l15 = lane & 15;
    half8 a[4];
#pragma unroll
    for (int kk = 0; kk < 4; ++kk)
        a[kk] = *(const half8*)(ut + l15 * 128 + kk * 32 + quad * 8);
#pragma unroll
    for (int tt = 0; tt < 2; ++tt) {               // GEMM1: wave does 2 of 8 n-tiles
        floatx4 acc = {0.f, 0.f, 0.f, 0.f};
        int n = (wave * 2 + tt) * 16 + l15;
#pragma unroll
        for (int kk = 0; kk < 4; ++kk) {
            half8 bb = *(const half8*)(W1 + n * 128 + kk * 32 + quad * 8);
            acc = __builtin_amdgcn_mfma_f32_16x16x32_f16(a[kk], bb, acc, 0, 0, 0);
        }
        float bias = bg[n];
#pragma unroll
        for (int i = 0; i < 4; ++i)
            z[(quad * 4 + i) * 128 + n] = (_Float16)fmaxf(acc[i] + bias, 0.f);
    }
    __syncthreads();
    half8 a2[4];
#pragma unroll
    for (int kk = 0; kk < 4; ++kk)
        a2[kk] = *(const half8*)(z + l15 * 128 + kk * 32 + quad * 8);
    {                                               // GEMM2: wave does 1 of 4 n-tiles
        floatx4 acc = {0.f, 0.f, 0.f, 0.f};
        int n = wave * 16 + l15;
#pragma unroll
        for (int kk = 0; kk < 4; ++kk) {
            half8 bb = *(const half8*)(W2 + n * 128 + kk * 32 + quad * 8);
            acc = __builtin_amdgcn_mfma_f32_16x16x32_f16(a2[kk], bb, acc, 0, 0, 0);
        }
        float bias = bfc[n];
#pragma unroll
        for (int i = 0; i < 4; ++i)
            out[(size_t)(nb + quad * 4 + i) * 64 + n] = acc[i] + bias;
    }
}

extern "C" void kernel_launch(void* const* d_in, const int* in_sizes, int n_in,
                              void* d_out, int out_size, void* d_ws, size_t ws_size,
                              hipStream_t stream) {
    (void)in_sizes; (void)n_in; (void)out_size; (void)ws_size;
    const float* h  = (const float*)d_in[0];
    const int*   ei = (const int*)d_in[1];
    const float* Wg = (const float*)d_in[2];
    const float* bg = (const float*)d_in[3];
    const float* Wf = (const float*)d_in[4];
    const float* bf = (const float*)d_in[5];
    float* out = (float*)d_out;

    char* ws = (char*)d_ws;
    int*      ptr   = (int*)(ws + O_PTR);
    int*      gfill = (int*)(ws + O_GF);
    float*    dinv  = (float*)(ws + O_DINV);
    int*      esrc  = (int*)(ws + O_ESRC);
    _Float16* W1    = (_Float16*)(ws + O_W1);
    _Float16* W2    = (_Float16*)(ws + O_W2);
    unsigned* staging = (unsigned*)(ws + O_STG);
    _Float16* h16   = (_Float16*)(ws + O_H16);

    hipMemsetAsync(gfill, 0, NBKT * sizeof(int), stream);
    k_binA<<<NBKT, 256, 0, stream>>>(ei, gfill, staging);
    k_binB<<<NBKT, 256, 0, stream>>>(staging, gfill, h, Wg, Wf,
                                     ptr, dinv, h16, W1, W2, esrc);
    k_aggF<<<N_NODES / 16, 256, 0, stream>>>(h16, ptr, esrc, dinv,
                                             W1, W2, bg, bf, out);
}